// Round 1
// baseline (1817.973 us; speedup 1.0000x reference)
//
#include <hip/hip_runtime.h>
#include <hip/hip_bf16.h>

// ---------------------------------------------------------------------------
// Attention (B=4, S=4096, d_model=d_attn=2048), fp32 in/out, bf16 MFMA compute.
// Stages:
//  1) cast x, Wq, Wk, Wv, Wo to bf16
//  2) Q = Xb@Wq^T, K = Xb@Wk^T          (gemm_bt, bf16 out)
//  3) Vt_b = Wv@Xb_b^T (per batch)      -> V stored transposed [d_attn][S]
//  4) per batch: Lg = (Qb_b@Kb_b^T)*scale (fp32 out)
//                P  = softmax_rows(Lg)    (bf16)
//                AO_b = P@Vt_b^T          (bf16)   [B^T layout thanks to Vt]
//  5) out = AO@Wo^T + bo (fp32)
// GEMM: m97-structure 128x128 tile, BK=32, 4 waves, global_load_lds staging.
// Workspace requirement: 384 MiB.
// ---------------------------------------------------------------------------

#define S_ 4096
#define DM_ 2048
#define DA_ 2048
#define NB_ 4

typedef __attribute__((ext_vector_type(8))) short short8;
typedef __attribute__((ext_vector_type(4))) float f32x4;
typedef __attribute__((ext_vector_type(8))) unsigned short ushort8;

__device__ __forceinline__ void gload_lds16(const void* g, void* l) {
  __builtin_amdgcn_global_load_lds(
      (const __attribute__((address_space(1))) void*)g,
      (__attribute__((address_space(3))) void*)l, 16, 0, 0);
}

__device__ __forceinline__ unsigned short f2bf(float f) {
  __hip_bfloat16 h = __float2bfloat16(f);
  return __builtin_bit_cast(unsigned short, h);
}

// C[M,N] = A[M,K] * B[N,K]^T  (A,B bf16 row-major, fp32 accumulate)
// EPI 0: C bf16 ; EPI 1: C fp32 * scale ; EPI 2: C fp32 + bias[col]
template <int EPI>
__global__ __launch_bounds__(256) void gemm_bt(
    const __hip_bfloat16* __restrict__ A, const __hip_bfloat16* __restrict__ Bm,
    void* __restrict__ Cv, const float* __restrict__ bias, int N, int K,
    int lda, int ldb, int ldc, float scale) {
  __shared__ alignas(16) __hip_bfloat16 As[128 * 32];
  __shared__ alignas(16) __hip_bfloat16 Bs[128 * 32];

  const int tid = threadIdx.x;
  const int lane = tid & 63;
  const int wave = tid >> 6;
  const int wm = wave >> 1, wn = wave & 1;

  const int nbn = N >> 7;
  const int bm = blockIdx.x / nbn;
  const int bn = blockIdx.x % nbn;

  // staging: each thread loads one 16B chunk per half-tile; LDS dest is
  // linear (wave-uniform base + lane*16) as global_load_lds requires.
  const int srow = tid >> 2;         // 0..63
  const int scol = (tid & 3) << 3;   // k-offset in elems

  const __hip_bfloat16* Ag0 = A + (size_t)(bm * 128 + srow) * lda + scol;
  const __hip_bfloat16* Ag1 = Ag0 + (size_t)64 * lda;
  const __hip_bfloat16* Bg0 = Bm + (size_t)(bn * 128 + srow) * ldb + scol;
  const __hip_bfloat16* Bg1 = Bg0 + (size_t)64 * ldb;
  __hip_bfloat16* Al0 = As + srow * 32 + scol;
  __hip_bfloat16* Al1 = Al0 + 64 * 32;
  __hip_bfloat16* Bl0 = Bs + srow * 32 + scol;
  __hip_bfloat16* Bl1 = Bl0 + 64 * 32;

  // MFMA fragment addressing (16x16x32): row/col = lane&15, k = (lane>>4)*8+j
  const int fr = lane & 15;
  const int fk = (lane >> 4) << 3;

  f32x4 acc[4][4] = {};

  for (int k0 = 0; k0 < K; k0 += 32) {
    gload_lds16(Ag0 + k0, Al0);
    gload_lds16(Ag1 + k0, Al1);
    gload_lds16(Bg0 + k0, Bl0);
    gload_lds16(Bg1 + k0, Bl1);
    __syncthreads();
    short8 aF[4], bF[4];
#pragma unroll
    for (int i = 0; i < 4; ++i)
      aF[i] = *(const short8*)(As + (wm * 64 + i * 16 + fr) * 32 + fk);
#pragma unroll
    for (int j = 0; j < 4; ++j)
      bF[j] = *(const short8*)(Bs + (wn * 64 + j * 16 + fr) * 32 + fk);
#pragma unroll
    for (int i = 0; i < 4; ++i)
#pragma unroll
      for (int j = 0; j < 4; ++j)
        acc[i][j] = __builtin_amdgcn_mfma_f32_16x16x32_bf16(aF[i], bF[j],
                                                            acc[i][j], 0, 0, 0);
    __syncthreads();
  }

  // C/D layout: col = lane&15, row = (lane>>4)*4 + reg   [verified m89/m91]
  const int r0 = bm * 128 + wm * 64 + ((lane >> 4) << 2);
  const int c0 = bn * 128 + wn * 64 + fr;
#pragma unroll
  for (int i = 0; i < 4; ++i) {
#pragma unroll
    for (int j = 0; j < 4; ++j) {
      const int row = r0 + i * 16;
      const int col = c0 + j * 16;
#pragma unroll
      for (int r = 0; r < 4; ++r) {
        const float v = acc[i][j][r];
        if (EPI == 0) {
          ((__hip_bfloat16*)Cv)[(size_t)(row + r) * ldc + col] =
              __float2bfloat16(v);
        } else if (EPI == 1) {
          ((float*)Cv)[(size_t)(row + r) * ldc + col] = v * scale;
        } else {
          ((float*)Cv)[(size_t)(row + r) * ldc + col] = v + bias[col];
        }
      }
    }
  }
}

// one block per row of 4096 fp32 logits -> bf16 probabilities
__global__ __launch_bounds__(256) void softmax_rows(
    const float* __restrict__ L, __hip_bfloat16* __restrict__ P) {
  const int t = threadIdx.x;
  const float* lr = L + (size_t)blockIdx.x * S_;
  const f32x4* lp = (const f32x4*)lr;
  f32x4 v[4];
#pragma unroll
  for (int i = 0; i < 4; ++i) v[i] = lp[t * 4 + i];
  float m = -1e30f;
#pragma unroll
  for (int i = 0; i < 4; ++i)
#pragma unroll
    for (int j = 0; j < 4; ++j) m = fmaxf(m, v[i][j]);
#pragma unroll
  for (int off = 32; off > 0; off >>= 1) m = fmaxf(m, __shfl_xor(m, off));
  __shared__ float red[8];
  const int wv = t >> 6;
  if ((t & 63) == 0) red[wv] = m;
  __syncthreads();
  m = fmaxf(fmaxf(red[0], red[1]), fmaxf(red[2], red[3]));
  float e[16];
  float s = 0.f;
#pragma unroll
  for (int i = 0; i < 4; ++i)
#pragma unroll
    for (int j = 0; j < 4; ++j) {
      const float ev = expf(v[i][j] - m);
      e[i * 4 + j] = ev;
      s += ev;
    }
#pragma unroll
  for (int off = 32; off > 0; off >>= 1) s += __shfl_xor(s, off);
  if ((t & 63) == 0) red[4 + wv] = s;
  __syncthreads();
  s = (red[4] + red[5]) + (red[6] + red[7]);
  const float inv = 1.0f / s;
  ushort8 o0, o1;
#pragma unroll
  for (int j = 0; j < 8; ++j) o0[j] = f2bf(e[j] * inv);
#pragma unroll
  for (int j = 0; j < 8; ++j) o1[j] = f2bf(e[8 + j] * inv);
  ushort8* pp = (ushort8*)(P + (size_t)blockIdx.x * S_) + t * 2;
  pp[0] = o0;
  pp[1] = o1;
}

__global__ __launch_bounds__(256) void cast_bf16(
    const float* __restrict__ in, __hip_bfloat16* __restrict__ out, long n) {
  long i = ((long)blockIdx.x * 256 + threadIdx.x) * 8;
  const long stride = (long)gridDim.x * 256 * 8;
  for (; i < n; i += stride) {
    const f32x4 a = *(const f32x4*)(in + i);
    const f32x4 b = *(const f32x4*)(in + i + 4);
    ushort8 o;
#pragma unroll
    for (int j = 0; j < 4; ++j) o[j] = f2bf(a[j]);
#pragma unroll
    for (int j = 0; j < 4; ++j) o[4 + j] = f2bf(b[j]);
    *(ushort8*)(out + i) = o;
  }
}

extern "C" void kernel_launch(void* const* d_in, const int* in_sizes, int n_in,
                              void* d_out, int out_size, void* d_ws,
                              size_t ws_size, hipStream_t stream) {
  (void)in_sizes; (void)n_in; (void)out_size; (void)ws_size;
  const float* x = (const float*)d_in[0];
  const float* Wq = (const float*)d_in[1];
  const float* Wk = (const float*)d_in[2];
  const float* Wv = (const float*)d_in[3];
  const float* Wo = (const float*)d_in[4];
  const float* bo = (const float*)d_in[5];
  float* out = (float*)d_out;

  char* ws = (char*)d_ws;  // needs 384 MiB
  __hip_bfloat16* Xb  = (__hip_bfloat16*)(ws);               // 64 MiB
  __hip_bfloat16* Qb  = (__hip_bfloat16*)(ws + (1ll << 26)); // 64 MiB
  __hip_bfloat16* Kb  = (__hip_bfloat16*)(ws + (2ll << 26)); // 64 MiB
  __hip_bfloat16* Vt  = (__hip_bfloat16*)(ws + (3ll << 26)); // 64 MiB
  __hip_bfloat16* Wqb = (__hip_bfloat16*)(ws + (4ll << 26));
  __hip_bfloat16* Wkb = (__hip_bfloat16*)(ws + (4ll << 26) + (1ll << 23));
  __hip_bfloat16* Wvb = (__hip_bfloat16*)(ws + (4ll << 26) + (2ll << 23));
  __hip_bfloat16* Wob = (__hip_bfloat16*)(ws + (4ll << 26) + (3ll << 23));
  float* Lg = (float*)(ws + (4ll << 26) + (4ll << 23));      // 64 MiB (1 batch)
  __hip_bfloat16* P =
      (__hip_bfloat16*)(ws + (4ll << 26) + (4ll << 23) + (1ll << 26)); // 32 MiB
  __hip_bfloat16* AO = Xb;  // x is dead after QKV projections; reuse

  const long nx = (long)NB_ * S_ * DM_;
  const long nw = (long)DA_ * DM_;
  cast_bf16<<<dim3(2048), dim3(256), 0, stream>>>(x, Xb, nx);
  cast_bf16<<<dim3(2048), dim3(256), 0, stream>>>(Wq, Wqb, nw);
  cast_bf16<<<dim3(2048), dim3(256), 0, stream>>>(Wk, Wkb, nw);
  cast_bf16<<<dim3(2048), dim3(256), 0, stream>>>(Wv, Wvb, nw);
  cast_bf16<<<dim3(2048), dim3(256), 0, stream>>>(Wo, Wob, nw);

  // Q, K projections: [16384,2048] = Xb @ W^T
  gemm_bt<0><<<dim3(2048), dim3(256), 0, stream>>>(
      Xb, Wqb, Qb, nullptr, 2048, 2048, 2048, 2048, 2048, 1.f);
  gemm_bt<0><<<dim3(2048), dim3(256), 0, stream>>>(
      Xb, Wkb, Kb, nullptr, 2048, 2048, 2048, 2048, 2048, 1.f);
  // Vt per batch: [2048,4096] = Wv @ Xb_b^T  (V stored transposed)
  for (int b = 0; b < NB_; ++b)
    gemm_bt<0><<<dim3(512), dim3(256), 0, stream>>>(
        Wvb, Xb + (size_t)b * S_ * DM_, Vt + (size_t)b * DA_ * S_, nullptr,
        4096, 2048, 2048, 2048, 4096, 1.f);

  const float scale = 0.022097086912079608f;  // 1/sqrt(d_model=2048)
  for (int b = 0; b < NB_; ++b) {
    gemm_bt<1><<<dim3(1024), dim3(256), 0, stream>>>(
        Qb + (size_t)b * S_ * DA_, Kb + (size_t)b * S_ * DA_, Lg, nullptr,
        4096, 2048, 2048, 2048, 4096, scale);
    softmax_rows<<<dim3(4096), dim3(256), 0, stream>>>(Lg, P);
    gemm_bt<0><<<dim3(512), dim3(256), 0, stream>>>(
        P, Vt + (size_t)b * DA_ * S_, AO + (size_t)b * S_ * DA_, nullptr,
        2048, 4096, 4096, 4096, 2048, 1.f);
  }
  // out = AO @ Wo^T + bo (fp32)
  gemm_bt<2><<<dim3(2048), dim3(256), 0, stream>>>(
      AO, Wob, out, bo, 2048, 2048, 2048, 2048, 2048, 1.f);
}

// Round 2
// 1075.803 us; speedup vs baseline: 1.6899x; 1.6899x over previous
//
#include <hip/hip_runtime.h>
#include <hip/hip_bf16.h>

// ---------------------------------------------------------------------------
// Attention (B=4, S=4096, d_model=d_attn=2048), fp32 in/out, bf16 MFMA.
// R1: all GEMMs moved to the 256x256 8-phase template (T2 st_16x32 swizzle +
// T3/T4 counted-vmcnt pipeline + T5 setprio), 512 threads, 128 KiB LDS.
// Staging schedule (per K-tile t, 4 phases):
//   ph0: read B(all 4 frags x2kk) + A(mi=0); stage A_h0(t+1) -> par^1
//   ph1: read A(mi=1);                      stage A_h1(t+1) -> par^1
//   ph2: read A(mi=2);                      stage B_h0(t+2) -> par
//   ph3: read A(mi=3);                      stage B_h1(t+2) -> par ; vmcnt(4)
// Boundary invariant: at each tile end, only the 2 B half-tiles of t+2 are
// outstanding (4 loads) -> vmcnt(4)+barrier guarantees tile t+1 fully staged.
// LDS swizzle: phys = sub*1024 + r*64 + ((c*2) ^ ((r&8)<<2)); gload_lds dest
// stays linear, global source column pre-swizzled (involution).
// Workspace: 384 MiB (480 MiB enables batched PV path).
// ---------------------------------------------------------------------------

#define S_ 4096
#define DM_ 2048
#define DA_ 2048
#define NB_ 4

typedef __attribute__((ext_vector_type(8))) short short8;
typedef __attribute__((ext_vector_type(4))) float f32x4;
typedef __attribute__((ext_vector_type(8))) unsigned short ushort8;

__device__ __forceinline__ void gload_lds16(const void* g, void* l) {
  __builtin_amdgcn_global_load_lds(
      (const __attribute__((address_space(1))) void*)g,
      (__attribute__((address_space(3))) void*)l, 16, 0, 0);
}

__device__ __forceinline__ unsigned short f2bf(float f) {
  __hip_bfloat16 h = __float2bfloat16(f);
  return __builtin_bit_cast(unsigned short, h);
}

#define STAGE_A(par, h, kt)                                                    \
  {                                                                            \
    const __hip_bfloat16* s0 = Asrc + (size_t)((h)*128) * lda + (kt)*64;       \
    gload_lds16(s0, dstA + (par)*32768 + (h)*16384);                           \
    gload_lds16(s0 + (size_t)64 * lda, dstA + (par)*32768 + (h)*16384 + 8192); \
  }
#define STAGE_B(par, h, kt)                                                    \
  {                                                                            \
    const __hip_bfloat16* s0 = Bsrc + (size_t)((h)*128) * ldb + (kt)*64;       \
    gload_lds16(s0, dstB + (par)*32768 + (h)*16384);                           \
    gload_lds16(s0 + (size_t)64 * ldb, dstB + (par)*32768 + (h)*16384 + 8192); \
  }
#define LDA_FRAG(par, mi, i, kk) \
  (*(const short8*)(ldsAr + (par)*32768 + ((mi)*2 + (i)) * 2048 + (kk)*1024))
#define LDB_FRAG(par, j, kk) \
  (*(const short8*)(ldsBr + (par)*32768 + (j)*2048 + (kk)*1024))

template <int PAR>
__device__ __forceinline__ void tile_body(
    int t, int NT, const __hip_bfloat16* __restrict__ Asrc,
    const __hip_bfloat16* __restrict__ Bsrc, int lda, int ldb, char* dstA,
    char* dstB, const char* ldsAr, const char* ldsBr, f32x4 (&acc)[8][4]) {
  const int tA = min(t + 1, NT - 1);
  const int tB = min(t + 2, NT - 1);
  short8 Bf[4][2], Af[2][2];

#define PHASE_TAIL(mi, LASTV)                                                 \
  __builtin_amdgcn_sched_barrier(0);                                          \
  __builtin_amdgcn_s_barrier();                                               \
  asm volatile("s_waitcnt lgkmcnt(0)" ::: "memory");                          \
  __builtin_amdgcn_sched_barrier(0);                                          \
  __builtin_amdgcn_s_setprio(1);                                              \
  _Pragma("unroll") for (int i = 0; i < 2; ++i)                               \
      _Pragma("unroll") for (int j = 0; j < 4; ++j)                           \
          _Pragma("unroll") for (int kk = 0; kk < 2; ++kk)                    \
              acc[(mi)*2 + i][j] = __builtin_amdgcn_mfma_f32_16x16x32_bf16(   \
                  Af[i][kk], Bf[j][kk], acc[(mi)*2 + i][j], 0, 0, 0);         \
  __builtin_amdgcn_s_setprio(0);                                              \
  __builtin_amdgcn_sched_barrier(0);                                          \
  if (LASTV) asm volatile("s_waitcnt vmcnt(4)" ::: "memory");                 \
  __builtin_amdgcn_s_barrier();                                               \
  __builtin_amdgcn_sched_barrier(0);

  // ph0: load all B frags + A(mi=0); stage A_h0(t+1)
#pragma unroll
  for (int j = 0; j < 4; ++j)
#pragma unroll
    for (int kk = 0; kk < 2; ++kk) Bf[j][kk] = LDB_FRAG(PAR, j, kk);
#pragma unroll
  for (int i = 0; i < 2; ++i)
#pragma unroll
    for (int kk = 0; kk < 2; ++kk) Af[i][kk] = LDA_FRAG(PAR, 0, i, kk);
  STAGE_A(PAR ^ 1, 0, tA);
  PHASE_TAIL(0, 0)

  // ph1: A(mi=1); stage A_h1(t+1)
#pragma unroll
  for (int i = 0; i < 2; ++i)
#pragma unroll
    for (int kk = 0; kk < 2; ++kk) Af[i][kk] = LDA_FRAG(PAR, 1, i, kk);
  STAGE_A(PAR ^ 1, 1, tA);
  PHASE_TAIL(1, 0)

  // ph2: A(mi=2); stage B_h0(t+2)
#pragma unroll
  for (int i = 0; i < 2; ++i)
#pragma unroll
    for (int kk = 0; kk < 2; ++kk) Af[i][kk] = LDA_FRAG(PAR, 2, i, kk);
  STAGE_B(PAR, 0, tB);
  PHASE_TAIL(2, 0)

  // ph3: A(mi=3); stage B_h1(t+2); boundary vmcnt(4)
#pragma unroll
  for (int i = 0; i < 2; ++i)
#pragma unroll
    for (int kk = 0; kk < 2; ++kk) Af[i][kk] = LDA_FRAG(PAR, 3, i, kk);
  STAGE_B(PAR, 1, tB);
  PHASE_TAIL(3, 1)
#undef PHASE_TAIL
}

// C[M,N] = A[M,K] * B[N,K]^T ; 256x256 tile, BK=64, 8 waves.
// EPI 0: C bf16 ; EPI 1: C fp32 * scale ; EPI 2: C fp32 + bias[col]
template <int EPI>
__global__ __launch_bounds__(512, 1) void gemm8(
    const __hip_bfloat16* __restrict__ A, const __hip_bfloat16* __restrict__ Bm,
    void* __restrict__ Cv, const float* __restrict__ bias, int N, int K,
    int lda, int ldb, int ldc, float scale, long strideA, long strideB,
    long strideC) {
  __shared__ alignas(16) char lds[131072];
  const int tid = threadIdx.x;
  const int lane = tid & 63;
  const int w = tid >> 6;
  const int wr = w >> 2, wc = w & 3;

  // bijective XCD swizzle (all our grids are divisible by 8)
  const int nwg = (int)gridDim.x;
  int wg = (int)blockIdx.x;
  wg = (wg & 7) * (nwg >> 3) + (wg >> 3);
  const int nbn = N >> 8;
  const int bm = wg / nbn, bn = wg % nbn;

  A += (long)blockIdx.y * strideA;
  Bm += (long)blockIdx.y * strideB;

  // staging source coords (pre-swizzled column: involution of read XOR)
  const int R = ((w >> 1) << 4) + (lane >> 2);
  const int Cc = ((w & 1) << 5) + (((lane & 3) << 3) ^ ((lane & 32) >> 1));
  const __hip_bfloat16* Asrc = A + (size_t)(bm * 256 + R) * lda + Cc;
  const __hip_bfloat16* Bsrc = Bm + (size_t)(bn * 256 + R) * ldb + Cc;
  char* dstA = lds + w * 1024 + lane * 16;
  char* dstB = dstA + 65536;

  // read-side swizzled base offsets
  const int fr = lane & 15;
  const int fk2 = (lane >> 4) << 4;  // k-chunk byte offset (0,16,32,48)
  const int rby = fr * 64 + (fk2 ^ ((fr & 8) << 2));
  const char* ldsAr = lds + wr * 16384 + rby;
  const char* ldsBr = lds + 65536 + (wc >> 1) * 16384 + (wc & 1) * 8192 + rby;

  const int NT = K >> 6;
  f32x4 acc[8][4] = {};

  // prologue: tile0 A+B, tile1 B  (12 loads); keep tile1's B in flight
  STAGE_A(0, 0, 0)
  STAGE_A(0, 1, 0)
  STAGE_B(0, 0, 0)
  STAGE_B(0, 1, 0)
  STAGE_B(1, 0, 1)
  STAGE_B(1, 1, 1)
  asm volatile("s_waitcnt vmcnt(4)" ::: "memory");
  __builtin_amdgcn_s_barrier();
  __builtin_amdgcn_sched_barrier(0);

  for (int t = 0; t < NT; t += 2) {
    tile_body<0>(t, NT, Asrc, Bsrc, lda, ldb, dstA, dstB, ldsAr, ldsBr, acc);
    tile_body<1>(t + 1, NT, Asrc, Bsrc, lda, ldb, dstA, dstB, ldsAr, ldsBr,
                 acc);
  }
  asm volatile("s_waitcnt vmcnt(0)" ::: "memory");

  // epilogue: C/D layout col=lane&15, row=(lane>>4)*4+reg  [verified m89/m91]
  float* Cf = (float*)Cv;
  __hip_bfloat16* Cb = (__hip_bfloat16*)Cv;
  const size_t cbase = (size_t)blockIdx.y * (size_t)strideC;
  const int r0 = bm * 256 + wr * 128 + ((lane >> 4) << 2);
  const int c0 = bn * 256 + wc * 64 + fr;
#pragma unroll
  for (int mi = 0; mi < 4; ++mi)
#pragma unroll
    for (int i = 0; i < 2; ++i)
#pragma unroll
      for (int j = 0; j < 4; ++j) {
        const int row = r0 + mi * 32 + i * 16;
        const int col = c0 + j * 16;
#pragma unroll
        for (int r = 0; r < 4; ++r) {
          const float v = acc[mi * 2 + i][j][r];
          if (EPI == 0)
            Cb[cbase + (size_t)(row + r) * ldc + col] = __float2bfloat16(v);
          else if (EPI == 1)
            Cf[cbase + (size_t)(row + r) * ldc + col] = v * scale;
          else
            Cf[cbase + (size_t)(row + r) * ldc + col] = v + bias[col];
        }
      }
}

// one block per row of 4096 fp32 logits -> bf16 probabilities
__global__ __launch_bounds__(256) void softmax_rows(
    const float* __restrict__ L, __hip_bfloat16* __restrict__ P) {
  const int t = threadIdx.x;
  const float* lr = L + (size_t)blockIdx.x * S_;
  const f32x4* lp = (const f32x4*)lr;
  f32x4 v[4];
#pragma unroll
  for (int i = 0; i < 4; ++i) v[i] = lp[t * 4 + i];
  float m = -1e30f;
#pragma unroll
  for (int i = 0; i < 4; ++i)
#pragma unroll
    for (int j = 0; j < 4; ++j) m = fmaxf(m, v[i][j]);
#pragma unroll
  for (int off = 32; off > 0; off >>= 1) m = fmaxf(m, __shfl_xor(m, off));
  __shared__ float red[8];
  const int wv = t >> 6;
  if ((t & 63) == 0) red[wv] = m;
  __syncthreads();
  m = fmaxf(fmaxf(red[0], red[1]), fmaxf(red[2], red[3]));
  float e[16];
  float s = 0.f;
#pragma unroll
  for (int i = 0; i < 4; ++i)
#pragma unroll
    for (int j = 0; j < 4; ++j) {
      const float ev = expf(v[i][j] - m);
      e[i * 4 + j] = ev;
      s += ev;
    }
#pragma unroll
  for (int off = 32; off > 0; off >>= 1) s += __shfl_xor(s, off);
  if ((t & 63) == 0) red[4 + wv] = s;
  __syncthreads();
  s = (red[4] + red[5]) + (red[6] + red[7]);
  const float inv = 1.0f / s;
  ushort8 o0, o1;
#pragma unroll
  for (int j = 0; j < 8; ++j) o0[j] = f2bf(e[j] * inv);
#pragma unroll
  for (int j = 0; j < 8; ++j) o1[j] = f2bf(e[8 + j] * inv);
  ushort8* pp = (ushort8*)(P + (size_t)blockIdx.x * S_) + t * 2;
  pp[0] = o0;
  pp[1] = o1;
}

__global__ __launch_bounds__(256) void cast_bf16(
    const float* __restrict__ in, __hip_bfloat16* __restrict__ out, long n) {
  long i = ((long)blockIdx.x * 256 + threadIdx.x) * 8;
  const long stride = (long)gridDim.x * 256 * 8;
  for (; i < n; i += stride) {
    const f32x4 a = *(const f32x4*)(in + i);
    const f32x4 b = *(const f32x4*)(in + i + 4);
    ushort8 o;
#pragma unroll
    for (int j = 0; j < 4; ++j) o[j] = f2bf(a[j]);
#pragma unroll
    for (int j = 0; j < 4; ++j) o[4 + j] = f2bf(b[j]);
    *(ushort8*)(out + i) = o;
  }
}

extern "C" void kernel_launch(void* const* d_in, const int* in_sizes, int n_in,
                              void* d_out, int out_size, void* d_ws,
                              size_t ws_size, hipStream_t stream) {
  (void)in_sizes; (void)n_in; (void)out_size;
  const float* x = (const float*)d_in[0];
  const float* Wq = (const float*)d_in[1];
  const float* Wk = (const float*)d_in[2];
  const float* Wv = (const float*)d_in[3];
  const float* Wo = (const float*)d_in[4];
  const float* bo = (const float*)d_in[5];
  float* out = (float*)d_out;

  char* ws = (char*)d_ws;  // needs 384 MiB; 480 MiB enables batched PV
  __hip_bfloat16* Xb  = (__hip_bfloat16*)(ws);               // 64 MiB
  __hip_bfloat16* Qb  = (__hip_bfloat16*)(ws + (1ll << 26)); // 64 MiB
  __hip_bfloat16* Kb  = (__hip_bfloat16*)(ws + (2ll << 26)); // 64 MiB
  __hip_bfloat16* Vt  = (__hip_bfloat16*)(ws + (3ll << 26)); // 64 MiB
  __hip_bfloat16* Wqb = (__hip_bfloat16*)(ws + (4ll << 26));
  __hip_bfloat16* Wkb = (__hip_bfloat16*)(ws + (4ll << 26) + (1ll << 23));
  __hip_bfloat16* Wvb = (__hip_bfloat16*)(ws + (4ll << 26) + (2ll << 23));
  __hip_bfloat16* Wob = (__hip_bfloat16*)(ws + (4ll << 26) + (3ll << 23));
  float* Lg = (float*)(ws + (4ll << 26) + (4ll << 23));      // 64 MiB
  __hip_bfloat16* Psm =
      (__hip_bfloat16*)(ws + (4ll << 26) + (4ll << 23) + (1ll << 26)); // 32 MiB
  __hip_bfloat16* AO = Xb;  // x dead after Q,K,Vt; reuse

  const bool bigP = ws_size >= (480ll << 20);
  __hip_bfloat16* Pbig = Psm;  // big path: 4 x 32 MiB starting at Psm

  const long nx = (long)NB_ * S_ * DM_;
  const long nw = (long)DA_ * DM_;
  cast_bf16<<<dim3(2048), dim3(256), 0, stream>>>(x, Xb, nx);
  cast_bf16<<<dim3(2048), dim3(256), 0, stream>>>(Wq, Wqb, nw);
  cast_bf16<<<dim3(2048), dim3(256), 0, stream>>>(Wk, Wkb, nw);
  cast_bf16<<<dim3(2048), dim3(256), 0, stream>>>(Wv, Wvb, nw);
  cast_bf16<<<dim3(2048), dim3(256), 0, stream>>>(Wo, Wob, nw);

  // Q, K projections: [16384,2048] = Xb @ W^T
  gemm8<0><<<dim3(512, 1), dim3(512), 0, stream>>>(
      Xb, Wqb, Qb, nullptr, 2048, 2048, 2048, 2048, 2048, 1.f, 0, 0, 0);
  gemm8<0><<<dim3(512, 1), dim3(512), 0, stream>>>(
      Xb, Wkb, Kb, nullptr, 2048, 2048, 2048, 2048, 2048, 1.f, 0, 0, 0);
  // Vt (batched over b): [2048,4096] = Wv @ Xb_b^T
  gemm8<0><<<dim3(128, NB_), dim3(512), 0, stream>>>(
      Wvb, Xb, Vt, nullptr, 4096, 2048, 2048, 2048, 4096, 1.f, 0,
      (long)S_ * DM_, (long)DA_ * S_);

  const float scale = 0.022097086912079608f;  // 1/sqrt(d_model=2048)
  for (int b = 0; b < NB_; ++b) {
    gemm8<1><<<dim3(256, 1), dim3(512), 0, stream>>>(
        Qb + (size_t)b * S_ * DA_, Kb + (size_t)b * S_ * DA_, Lg, nullptr,
        4096, 2048, 2048, 2048, 4096, scale, 0, 0, 0);
    __hip_bfloat16* Pb = bigP ? Pbig + (size_t)b * S_ * S_ : Psm;
    softmax_rows<<<dim3(4096), dim3(256), 0, stream>>>(Lg, Pb);
    if (!bigP) {
      gemm8<0><<<dim3(128, 1), dim3(512), 0, stream>>>(
          Psm, Vt + (size_t)b * DA_ * S_, AO + (size_t)b * S_ * DA_, nullptr,
          2048, 4096, 4096, 4096, 2048, 1.f, 0, 0, 0);
    }
  }
  if (bigP) {
    gemm8<0><<<dim3(128, NB_), dim3(512), 0, stream>>>(
        Pbig, Vt, AO, nullptr, 2048, 4096, 4096, 4096, 2048, 1.f,
        (long)S_ * S_, (long)DA_ * S_, (long)S_ * DA_);
  }
  // out = AO @ Wo^T + bo (fp32)
  gemm8<2><<<dim3(512, 1), dim3(512), 0, stream>>>(
      AO, Wob, out, bo, 2048, 2048, 2048, 2048, 2048, 1.f, 0, 0, 0);
}

// Round 3
// 1041.201 us; speedup vs baseline: 1.7460x; 1.0332x over previous
//
#include <hip/hip_runtime.h>
#include <hip/hip_bf16.h>
#include <hip/hip_fp16.h>

// ---------------------------------------------------------------------------
// Attention (B=4, S=4096, d_model=d_attn=2048), fp32 in/out, bf16 MFMA.
// R2: counted lgkmcnt(4) + 1-phase-ahead A-prefetch in the 8-phase GEMM;
//     fp16 logits with in-place softmax (fp16 -> bf16, same buffer);
//     fused Q+K projection; fully batched QK^T / softmax / PV;
//     distinct TAG per GEMM instantiation for rocprof attribution.
// Workspace: 416 MiB batched path (per-batch fallback at 320 MiB).
// ---------------------------------------------------------------------------

#define S_ 4096
#define DM_ 2048
#define DA_ 2048
#define NB_ 4

typedef __attribute__((ext_vector_type(8))) short short8;
typedef __attribute__((ext_vector_type(4))) float f32x4;
typedef __attribute__((ext_vector_type(8))) unsigned short ushort8;

__device__ __forceinline__ void gload_lds16(const void* g, void* l) {
  __builtin_amdgcn_global_load_lds(
      (const __attribute__((address_space(1))) void*)g,
      (__attribute__((address_space(3))) void*)l, 16, 0, 0);
}

__device__ __forceinline__ unsigned short f2bf(float f) {
  __hip_bfloat16 h = __float2bfloat16(f);
  return __builtin_bit_cast(unsigned short, h);
}

#define STAGE_A(par, h, kt)                                                    \
  {                                                                            \
    const __hip_bfloat16* s0 = Asrc + (size_t)((h)*128) * lda + (kt)*64;       \
    gload_lds16(s0, dstA + (par)*32768 + (h)*16384);                           \
    gload_lds16(s0 + (size_t)64 * lda, dstA + (par)*32768 + (h)*16384 + 8192); \
  }
#define STAGE_B(par, h, kt)                                                    \
  {                                                                            \
    const __hip_bfloat16* s0 = Bsrc + (size_t)((h)*128) * ldb + (kt)*64;       \
    gload_lds16(s0, dstB + (par)*32768 + (h)*16384);                           \
    gload_lds16(s0 + (size_t)64 * ldb, dstB + (par)*32768 + (h)*16384 + 8192); \
  }
#define LDA_FRAG(par, mi, i, kk) \
  (*(const short8*)(ldsAr + (par)*32768 + ((mi)*2 + (i)) * 2048 + (kk)*1024))
#define LDB_FRAG(par, j, kk) \
  (*(const short8*)(ldsBr + (par)*32768 + (j)*2048 + (kk)*1024))

#define MFMA_PHASE(mi, AF)                                                  \
  __builtin_amdgcn_s_setprio(1);                                            \
  _Pragma("unroll") for (int i = 0; i < 2; ++i)                             \
      _Pragma("unroll") for (int j = 0; j < 4; ++j)                         \
          _Pragma("unroll") for (int kk = 0; kk < 2; ++kk)                  \
              acc[(mi)*2 + i][j] = __builtin_amdgcn_mfma_f32_16x16x32_bf16( \
                  AF[i][kk], Bf[j][kk], acc[(mi)*2 + i][j], 0, 0, 0);       \
  __builtin_amdgcn_s_setprio(0);                                            \
  __builtin_amdgcn_sched_barrier(0);

template <int PAR>
__device__ __forceinline__ void tile_body(
    int t, int NT, const __hip_bfloat16* __restrict__ Asrc,
    const __hip_bfloat16* __restrict__ Bsrc, int lda, int ldb, char* dstA,
    char* dstB, const char* ldsAr, const char* ldsBr, f32x4 (&acc)[8][4]) {
  const int tA = min(t + 1, NT - 1);
  const int tB = min(t + 2, NT - 1);
  short8 Bf[4][2], A0[2][2], A1[2][2];

  // ph0: read B(8)+A(mi0)->A0 | prefetch A(mi1)->A1; stage A.h0(t+1)
#pragma unroll
  for (int j = 0; j < 4; ++j)
#pragma unroll
    for (int kk = 0; kk < 2; ++kk) Bf[j][kk] = LDB_FRAG(PAR, j, kk);
#pragma unroll
  for (int i = 0; i < 2; ++i)
#pragma unroll
    for (int kk = 0; kk < 2; ++kk) A0[i][kk] = LDA_FRAG(PAR, 0, i, kk);
  __builtin_amdgcn_sched_barrier(0);  // pin: B+A0 issued before A1
#pragma unroll
  for (int i = 0; i < 2; ++i)
#pragma unroll
    for (int kk = 0; kk < 2; ++kk) A1[i][kk] = LDA_FRAG(PAR, 1, i, kk);
  STAGE_A(PAR ^ 1, 0, tA);
  __builtin_amdgcn_sched_barrier(0);
  __builtin_amdgcn_s_barrier();
  asm volatile("s_waitcnt lgkmcnt(4)" ::: "memory");  // B+A0 landed, A1 flies
  __builtin_amdgcn_sched_barrier(0);
  MFMA_PHASE(0, A0)
  __builtin_amdgcn_s_barrier();
  __builtin_amdgcn_sched_barrier(0);

  // ph1: prefetch A(mi2)->A0; stage A.h1(t+1); MFMA(mi1, A1)
#pragma unroll
  for (int i = 0; i < 2; ++i)
#pragma unroll
    for (int kk = 0; kk < 2; ++kk) A0[i][kk] = LDA_FRAG(PAR, 2, i, kk);
  STAGE_A(PAR ^ 1, 1, tA);
  __builtin_amdgcn_sched_barrier(0);
  __builtin_amdgcn_s_barrier();
  asm volatile("s_waitcnt lgkmcnt(4)" ::: "memory");  // A1 landed, A0' flies
  __builtin_amdgcn_sched_barrier(0);
  MFMA_PHASE(1, A1)
  __builtin_amdgcn_s_barrier();
  __builtin_amdgcn_sched_barrier(0);

  // ph2: prefetch A(mi3)->A1; stage B.h0(t+2); MFMA(mi2, A0)
#pragma unroll
  for (int i = 0; i < 2; ++i)
#pragma unroll
    for (int kk = 0; kk < 2; ++kk) A1[i][kk] = LDA_FRAG(PAR, 3, i, kk);
  STAGE_B(PAR, 0, tB);
  __builtin_amdgcn_sched_barrier(0);
  __builtin_amdgcn_s_barrier();
  asm volatile("s_waitcnt lgkmcnt(4)" ::: "memory");  // A0' landed, A1' flies
  __builtin_amdgcn_sched_barrier(0);
  MFMA_PHASE(2, A0)
  __builtin_amdgcn_s_barrier();
  __builtin_amdgcn_sched_barrier(0);

  // ph3: stage B.h1(t+2); MFMA(mi3, A1); boundary vmcnt(4)
  STAGE_B(PAR, 1, tB);
  __builtin_amdgcn_sched_barrier(0);
  __builtin_amdgcn_s_barrier();
  asm volatile("s_waitcnt lgkmcnt(0)" ::: "memory");
  __builtin_amdgcn_sched_barrier(0);
  MFMA_PHASE(3, A1)
  asm volatile("s_waitcnt vmcnt(4)" ::: "memory");
  __builtin_amdgcn_s_barrier();
  __builtin_amdgcn_sched_barrier(0);
}

// C[M,N] = A[M,K] * B[N,K]^T ; 256x256 tile, BK=64, 8 waves.
// EPI 0: C bf16 ; EPI 1: C fp16 * scale ; EPI 2: C fp32 + bias[col]
template <int EPI, int TAG>
__global__ __launch_bounds__(512, 2) void gemm8(
    const __hip_bfloat16* __restrict__ A, const __hip_bfloat16* __restrict__ Bm,
    void* __restrict__ Cv, const float* __restrict__ bias, int N, int K,
    int lda, int ldb, int ldc, float scale, long strideA, long strideB,
    long strideC) {
  __shared__ alignas(16) char lds[131072];
  const int tid = threadIdx.x;
  const int lane = tid & 63;
  const int w = tid >> 6;
  const int wr = w >> 2, wc = w & 3;

  // bijective XCD swizzle (all grids divisible by 8)
  const int nwg = (int)gridDim.x;
  int wg = (int)blockIdx.x;
  wg = (wg & 7) * (nwg >> 3) + (wg >> 3);
  const int nbn = N >> 8;
  const int bm = wg / nbn, bn = wg % nbn;

  A += (long)blockIdx.y * strideA;
  Bm += (long)blockIdx.y * strideB;

  // staging source coords (pre-swizzled column: involution of read XOR)
  const int R = ((w >> 1) << 4) + (lane >> 2);
  const int Cc = ((w & 1) << 5) + (((lane & 3) << 3) ^ ((lane & 32) >> 1));
  const __hip_bfloat16* Asrc = A + (size_t)(bm * 256 + R) * lda + Cc;
  const __hip_bfloat16* Bsrc = Bm + (size_t)(bn * 256 + R) * ldb + Cc;
  char* dstA = lds + w * 1024 + lane * 16;
  char* dstB = dstA + 65536;

  // read-side swizzled base offsets
  const int fr = lane & 15;
  const int fk2 = (lane >> 4) << 4;
  const int rby = fr * 64 + (fk2 ^ ((fr & 8) << 2));
  const char* ldsAr = lds + wr * 16384 + rby;
  const char* ldsBr = lds + 65536 + (wc >> 1) * 16384 + (wc & 1) * 8192 + rby;

  const int NT = K >> 6;
  f32x4 acc[8][4] = {};

  // prologue: tile0 A+B, tile1 B ; keep tile1's B in flight
  STAGE_A(0, 0, 0)
  STAGE_A(0, 1, 0)
  STAGE_B(0, 0, 0)
  STAGE_B(0, 1, 0)
  STAGE_B(1, 0, 1)
  STAGE_B(1, 1, 1)
  asm volatile("s_waitcnt vmcnt(4)" ::: "memory");
  __builtin_amdgcn_s_barrier();
  __builtin_amdgcn_sched_barrier(0);

  for (int t = 0; t < NT; t += 2) {
    tile_body<0>(t, NT, Asrc, Bsrc, lda, ldb, dstA, dstB, ldsAr, ldsBr, acc);
    tile_body<1>(t + 1, NT, Asrc, Bsrc, lda, ldb, dstA, dstB, ldsAr, ldsBr,
                 acc);
  }
  asm volatile("s_waitcnt vmcnt(0)" ::: "memory");

  // epilogue: C/D layout col=lane&15, row=(lane>>4)*4+reg  [verified m89/m91]
  float* Cf = (float*)Cv;
  __hip_bfloat16* Cb = (__hip_bfloat16*)Cv;
  __half* Ch = (__half*)Cv;
  const size_t cbase = (size_t)blockIdx.y * (size_t)strideC;
  const int r0 = bm * 256 + wr * 128 + ((lane >> 4) << 2);
  const int c0 = bn * 256 + wc * 64 + fr;
#pragma unroll
  for (int mi = 0; mi < 4; ++mi)
#pragma unroll
    for (int i = 0; i < 2; ++i)
#pragma unroll
      for (int j = 0; j < 4; ++j) {
        const int row = r0 + mi * 32 + i * 16;
        const int col = c0 + j * 16;
#pragma unroll
        for (int r = 0; r < 4; ++r) {
          const float v = acc[mi * 2 + i][j][r];
          if (EPI == 0)
            Cb[cbase + (size_t)(row + r) * ldc + col] = __float2bfloat16(v);
          else if (EPI == 1)
            Ch[cbase + (size_t)(row + r) * ldc + col] = __float2half(v * scale);
          else
            Cf[cbase + (size_t)(row + r) * ldc + col] = v + bias[col];
        }
      }
}

// one block per 4096-wide row: read fp16 logits, write bf16 probs IN PLACE
__global__ __launch_bounds__(256) void softmax_inplace(void* __restrict__ buf) {
  const int t = threadIdx.x;
  unsigned short* rp = (unsigned short*)buf + (size_t)blockIdx.x * S_;
  ushort8 h0 = ((const ushort8*)rp)[t * 2];
  ushort8 h1 = ((const ushort8*)rp)[t * 2 + 1];
  float v[16];
#pragma unroll
  for (int j = 0; j < 8; ++j) {
    v[j] = __half2float(__builtin_bit_cast(__half, (unsigned short)h0[j]));
    v[8 + j] = __half2float(__builtin_bit_cast(__half, (unsigned short)h1[j]));
  }
  float m = -1e30f;
#pragma unroll
  for (int j = 0; j < 16; ++j) m = fmaxf(m, v[j]);
#pragma unroll
  for (int off = 32; off > 0; off >>= 1) m = fmaxf(m, __shfl_xor(m, off));
  __shared__ float red[8];
  const int wv = t >> 6;
  if ((t & 63) == 0) red[wv] = m;
  __syncthreads();
  m = fmaxf(fmaxf(red[0], red[1]), fmaxf(red[2], red[3]));
  float e[16], s = 0.f;
#pragma unroll
  for (int j = 0; j < 16; ++j) {
    e[j] = __expf(v[j] - m);
    s += e[j];
  }
#pragma unroll
  for (int off = 32; off > 0; off >>= 1) s += __shfl_xor(s, off);
  if ((t & 63) == 0) red[4 + wv] = s;
  __syncthreads();
  s = (red[4] + red[5]) + (red[6] + red[7]);
  const float inv = 1.0f / s;
  ushort8 o0, o1;
#pragma unroll
  for (int j = 0; j < 8; ++j) {
    o0[j] = f2bf(e[j] * inv);
    o1[j] = f2bf(e[8 + j] * inv);
  }
  ((ushort8*)rp)[t * 2] = o0;
  ((ushort8*)rp)[t * 2 + 1] = o1;
}

__global__ __launch_bounds__(256) void cast_bf16(
    const float* __restrict__ in, __hip_bfloat16* __restrict__ out, long n) {
  long i = ((long)blockIdx.x * 256 + threadIdx.x) * 8;
  const long stride = (long)gridDim.x * 256 * 8;
  for (; i < n; i += stride) {
    const f32x4 a = *(const f32x4*)(in + i);
    const f32x4 b = *(const f32x4*)(in + i + 4);
    ushort8 o;
#pragma unroll
    for (int j = 0; j < 4; ++j) o[j] = f2bf(a[j]);
#pragma unroll
    for (int j = 0; j < 4; ++j) o[4 + j] = f2bf(b[j]);
    *(ushort8*)(out + i) = o;
  }
}

extern "C" void kernel_launch(void* const* d_in, const int* in_sizes, int n_in,
                              void* d_out, int out_size, void* d_ws,
                              size_t ws_size, hipStream_t stream) {
  (void)in_sizes; (void)n_in; (void)out_size;
  const float* x = (const float*)d_in[0];
  const float* Wq = (const float*)d_in[1];
  const float* Wk = (const float*)d_in[2];
  const float* Wv = (const float*)d_in[3];
  const float* Wo = (const float*)d_in[4];
  const float* bo = (const float*)d_in[5];
  float* out = (float*)d_out;

  const long MB = 1ll << 20;
  char* ws = (char*)d_ws;
  __hip_bfloat16* Xb   = (__hip_bfloat16*)(ws);             // 64 MiB
  __hip_bfloat16* QKb  = (__hip_bfloat16*)(ws + 64 * MB);   // 128 MiB (Q|K)
  __hip_bfloat16* Vt   = (__hip_bfloat16*)(ws + 192 * MB);  // 64 MiB
  __hip_bfloat16* Wqkb = (__hip_bfloat16*)(ws + 256 * MB);  // 16 MiB
  __hip_bfloat16* Wvb  = (__hip_bfloat16*)(ws + 272 * MB);  // 8 MiB
  __hip_bfloat16* Wob  = (__hip_bfloat16*)(ws + 280 * MB);  // 8 MiB
  char* LgP            = ws + 288 * MB;  // 128 MiB batched / 32 MiB per-batch
  __hip_bfloat16* AO = Xb;  // x dead after projections; reuse

  const bool batched = ws_size >= (size_t)(416 * MB);

  const long nx = (long)NB_ * S_ * DM_;
  const long nw = (long)DA_ * DM_;
  cast_bf16<<<dim3(2048), dim3(256), 0, stream>>>(x, Xb, nx);
  cast_bf16<<<dim3(2048), dim3(256), 0, stream>>>(Wq, Wqkb, nw);
  cast_bf16<<<dim3(2048), dim3(256), 0, stream>>>(Wk, Wqkb + nw, nw);
  cast_bf16<<<dim3(2048), dim3(256), 0, stream>>>(Wv, Wvb, nw);
  cast_bf16<<<dim3(2048), dim3(256), 0, stream>>>(Wo, Wob, nw);

  // fused Q|K projection: [16384, 4096] = Xb @ [Wq;Wk]^T
  gemm8<0, 0><<<dim3(1024, 1), dim3(512), 0, stream>>>(
      Xb, Wqkb, QKb, nullptr, 4096, 2048, 2048, 2048, 4096, 1.f, 0, 0, 0);
  // Vt (batched): [2048, 4096] = Wv @ Xb_b^T
  gemm8<0, 1><<<dim3(128, NB_), dim3(512), 0, stream>>>(
      Wvb, Xb, Vt, nullptr, 4096, 2048, 2048, 2048, 4096, 1.f, 0,
      (long)S_ * DM_, (long)DA_ * S_);

  const float scale = 0.022097086912079608f;  // 1/sqrt(d_model=2048)
  if (batched) {
    gemm8<1, 2><<<dim3(256, NB_), dim3(512), 0, stream>>>(
        QKb, QKb + DA_, LgP, nullptr, 4096, 2048, 4096, 4096, 4096, scale,
        (long)S_ * 2 * DA_, (long)S_ * 2 * DA_, (long)S_ * S_);
    softmax_inplace<<<dim3(NB_ * S_), dim3(256), 0, stream>>>(LgP);
    gemm8<0, 3><<<dim3(128, NB_), dim3(512), 0, stream>>>(
        (const __hip_bfloat16*)LgP, Vt, AO, nullptr, 2048, 4096, 4096, 4096,
        2048, 1.f, (long)S_ * S_, (long)DA_ * S_, (long)S_ * DA_);
  } else {
    for (int b = 0; b < NB_; ++b) {
      const __hip_bfloat16* Qb = QKb + (size_t)b * S_ * 2 * DA_;
      gemm8<1, 2><<<dim3(256, 1), dim3(512), 0, stream>>>(
          Qb, Qb + DA_, LgP, nullptr, 4096, 2048, 4096, 4096, 4096, scale, 0,
          0, 0);
      softmax_inplace<<<dim3(S_), dim3(256), 0, stream>>>(LgP);
      gemm8<0, 3><<<dim3(128, 1), dim3(512), 0, stream>>>(
          (const __hip_bfloat16*)LgP, Vt + (size_t)b * DA_ * S_,
          AO + (size_t)b * S_ * DA_, nullptr, 2048, 4096, 4096, 4096, 2048,
          1.f, 0, 0, 0);
    }
  }
  // out = AO @ Wo^T + bo (fp32)
  gemm8<2, 4><<<dim3(512, 1), dim3(512), 0, stream>>>(
      AO, Wob, out, bo, 2048, 2048, 2048, 2048, 2048, 1.f, 0, 0, 0);
}

// Round 4
// 1027.047 us; speedup vs baseline: 1.7701x; 1.0138x over previous
//
#include <hip/hip_runtime.h>
#include <hip/hip_bf16.h>
#include <hip/hip_fp16.h>

// ---------------------------------------------------------------------------
// Attention (B=4, S=4096, d_model=d_attn=2048), fp32 in/out, bf16 MFMA.
// R3: m201-faithful staging (1 half-tile/phase, depth t+2, vmcnt(6) boundary,
//     3 half-tiles in flight); reverted R2's A-prefetch/lgkmcnt(4);
//     named per-stage GEMM wrappers for rocprof attribution; single fused
//     cast kernel. fp16 logits + in-place softmax; fully batched.
// Workspace: 416 MiB batched path (per-batch fallback at 320 MiB).
// ---------------------------------------------------------------------------

#define S_ 4096
#define DM_ 2048
#define DA_ 2048
#define NB_ 4

typedef __attribute__((ext_vector_type(8))) short short8;
typedef __attribute__((ext_vector_type(4))) float f32x4;
typedef __attribute__((ext_vector_type(8))) unsigned short ushort8;

__device__ __forceinline__ void gload_lds16(const void* g, void* l) {
  __builtin_amdgcn_global_load_lds(
      (const __attribute__((address_space(1))) void*)g,
      (__attribute__((address_space(3))) void*)l, 16, 0, 0);
}

__device__ __forceinline__ unsigned short f2bf(float f) {
  __hip_bfloat16 h = __float2bfloat16(f);
  return __builtin_bit_cast(unsigned short, h);
}

#define STAGE_A(par, h, kt)                                                    \
  {                                                                            \
    const __hip_bfloat16* s0 = Asrc + (size_t)((h)*128) * lda + (kt)*64;       \
    gload_lds16(s0, dstA + (par)*32768 + (h)*16384);                           \
    gload_lds16(s0 + (size_t)64 * lda, dstA + (par)*32768 + (h)*16384 + 8192); \
  }
#define STAGE_B(par, h, kt)                                                    \
  {                                                                            \
    const __hip_bfloat16* s0 = Bsrc + (size_t)((h)*128) * ldb + (kt)*64;       \
    gload_lds16(s0, dstB + (par)*32768 + (h)*16384);                           \
    gload_lds16(s0 + (size_t)64 * ldb, dstB + (par)*32768 + (h)*16384 + 8192); \
  }
#define LDA_FRAG(par, mi, i, kk) \
  (*(const short8*)(ldsAr + (par)*32768 + ((mi)*2 + (i)) * 2048 + (kk)*1024))
#define LDB_FRAG(par, j, kk) \
  (*(const short8*)(ldsBr + (par)*32768 + (j)*2048 + (kk)*1024))

#define MFMA_PHASE(mi)                                                      \
  __builtin_amdgcn_s_setprio(1);                                            \
  _Pragma("unroll") for (int i = 0; i < 2; ++i)                             \
      _Pragma("unroll") for (int j = 0; j < 4; ++j)                         \
          _Pragma("unroll") for (int kk = 0; kk < 2; ++kk)                  \
              acc[(mi)*2 + i][j] = __builtin_amdgcn_mfma_f32_16x16x32_bf16( \
                  Af[i][kk], Bf[j][kk], acc[(mi)*2 + i][j], 0, 0, 0);       \
  __builtin_amdgcn_s_setprio(0);                                            \
  __builtin_amdgcn_sched_barrier(0);

#define PHASE_SYNC_PRE                                 \
  __builtin_amdgcn_sched_barrier(0);                   \
  __builtin_amdgcn_s_barrier();                        \
  asm volatile("s_waitcnt lgkmcnt(0)" ::: "memory");   \
  __builtin_amdgcn_sched_barrier(0);

// Per K-tile t (phases ph0..ph3), staging schedule (m201-faithful):
//   ph0: read B(8)+A(mi0); stage A.h1(t+1) -> PAR^1
//   ph1: read A(mi1);      stage B.h0(t+2) -> PAR
//   ph2: read A(mi2);      stage B.h1(t+2) -> PAR
//   ph3: read A(mi3);      stage A.h0(t+2) -> PAR ; vmcnt(6) at boundary
// Steady state: 3 half-tiles (6 loads) in flight across each boundary;
// vmcnt(6) drains exactly tile t+1's 8 loads. Tail clamps are idempotent.
template <int PAR>
__device__ __forceinline__ void tile_body(
    int t, int NT, const __hip_bfloat16* __restrict__ Asrc,
    const __hip_bfloat16* __restrict__ Bsrc, int lda, int ldb, char* dstA,
    char* dstB, const char* ldsAr, const char* ldsBr, f32x4 (&acc)[8][4]) {
  const int tn = min(t + 1, NT - 1);
  const int tf = min(t + 2, NT - 1);
  short8 Bf[4][2], Af[2][2];

  // ph0
#pragma unroll
  for (int j = 0; j < 4; ++j)
#pragma unroll
    for (int kk = 0; kk < 2; ++kk) Bf[j][kk] = LDB_FRAG(PAR, j, kk);
#pragma unroll
  for (int i = 0; i < 2; ++i)
#pragma unroll
    for (int kk = 0; kk < 2; ++kk) Af[i][kk] = LDA_FRAG(PAR, 0, i, kk);
  STAGE_A(PAR ^ 1, 1, tn);
  PHASE_SYNC_PRE
  MFMA_PHASE(0)
  __builtin_amdgcn_s_barrier();
  __builtin_amdgcn_sched_barrier(0);

  // ph1
#pragma unroll
  for (int i = 0; i < 2; ++i)
#pragma unroll
    for (int kk = 0; kk < 2; ++kk) Af[i][kk] = LDA_FRAG(PAR, 1, i, kk);
  STAGE_B(PAR, 0, tf);
  PHASE_SYNC_PRE
  MFMA_PHASE(1)
  __builtin_amdgcn_s_barrier();
  __builtin_amdgcn_sched_barrier(0);

  // ph2
#pragma unroll
  for (int i = 0; i < 2; ++i)
#pragma unroll
    for (int kk = 0; kk < 2; ++kk) Af[i][kk] = LDA_FRAG(PAR, 2, i, kk);
  STAGE_B(PAR, 1, tf);
  PHASE_SYNC_PRE
  MFMA_PHASE(2)
  __builtin_amdgcn_s_barrier();
  __builtin_amdgcn_sched_barrier(0);

  // ph3
#pragma unroll
  for (int i = 0; i < 2; ++i)
#pragma unroll
    for (int kk = 0; kk < 2; ++kk) Af[i][kk] = LDA_FRAG(PAR, 3, i, kk);
  STAGE_A(PAR, 0, tf);
  PHASE_SYNC_PRE
  MFMA_PHASE(3)
  asm volatile("s_waitcnt vmcnt(6)" ::: "memory");
  __builtin_amdgcn_s_barrier();
  __builtin_amdgcn_sched_barrier(0);
}

// C[M,N] = A[M,K] * B[N,K]^T ; 256x256 tile, BK=64, 8 waves.
// EPI 0: C bf16 ; EPI 1: C fp16 * scale ; EPI 2: C fp32 + bias[col]
template <int EPI>
__device__ __forceinline__ void gemm8_body(
    const __hip_bfloat16* __restrict__ A, const __hip_bfloat16* __restrict__ Bm,
    void* __restrict__ Cv, const float* __restrict__ bias, int N, int K,
    int lda, int ldb, int ldc, float scale, long strideA, long strideB,
    long strideC) {
  __shared__ alignas(16) char lds[131072];
  const int tid = threadIdx.x;
  const int lane = tid & 63;
  const int w = tid >> 6;
  const int wr = w >> 2, wc = w & 3;

  // bijective XCD swizzle (all grids divisible by 8)
  const int nwg = (int)gridDim.x;
  int wg = (int)blockIdx.x;
  wg = (wg & 7) * (nwg >> 3) + (wg >> 3);
  const int nbn = N >> 8;
  const int bm = wg / nbn, bn = wg % nbn;

  A += (long)blockIdx.y * strideA;
  Bm += (long)blockIdx.y * strideB;

  // staging source coords (pre-swizzled column: involution of read XOR)
  const int R = ((w >> 1) << 4) + (lane >> 2);
  const int Cc = ((w & 1) << 5) + (((lane & 3) << 3) ^ ((lane & 32) >> 1));
  const __hip_bfloat16* Asrc = A + (size_t)(bm * 256 + R) * lda + Cc;
  const __hip_bfloat16* Bsrc = Bm + (size_t)(bn * 256 + R) * ldb + Cc;
  char* dstA = lds + w * 1024 + lane * 16;
  char* dstB = dstA + 65536;

  // read-side swizzled base offsets
  const int fr = lane & 15;
  const int fk2 = (lane >> 4) << 4;
  const int rby = fr * 64 + (fk2 ^ ((fr & 8) << 2));
  const char* ldsAr = lds + wr * 16384 + rby;
  const char* ldsBr = lds + 65536 + (wc >> 1) * 16384 + (wc & 1) * 8192 + rby;

  const int NT = K >> 6;
  f32x4 acc[8][4] = {};

  // prologue: T0 all 4 halves -> par0; T1 B.h0,B.h1,A.h0 -> par1 (14 loads);
  // vmcnt(6) drains T0, leaves T1's 3 half-tiles in flight (steady state).
  STAGE_B(0, 0, 0)
  STAGE_B(0, 1, 0)
  STAGE_A(0, 0, 0)
  STAGE_A(0, 1, 0)
  STAGE_B(1, 0, 1)
  STAGE_B(1, 1, 1)
  STAGE_A(1, 0, 1)
  asm volatile("s_waitcnt vmcnt(6)" ::: "memory");
  __builtin_amdgcn_s_barrier();
  __builtin_amdgcn_sched_barrier(0);

  for (int t = 0; t < NT; t += 2) {
    tile_body<0>(t, NT, Asrc, Bsrc, lda, ldb, dstA, dstB, ldsAr, ldsBr, acc);
    tile_body<1>(t + 1, NT, Asrc, Bsrc, lda, ldb, dstA, dstB, ldsAr, ldsBr,
                 acc);
  }
  asm volatile("s_waitcnt vmcnt(0)" ::: "memory");

  // epilogue: C/D layout col=lane&15, row=(lane>>4)*4+reg  [verified m89/m91]
  float* Cf = (float*)Cv;
  __hip_bfloat16* Cb = (__hip_bfloat16*)Cv;
  __half* Ch = (__half*)Cv;
  const size_t cbase = (size_t)blockIdx.y * (size_t)strideC;
  const int r0 = bm * 256 + wr * 128 + ((lane >> 4) << 2);
  const int c0 = bn * 256 + wc * 64 + fr;
#pragma unroll
  for (int mi = 0; mi < 4; ++mi)
#pragma unroll
    for (int i = 0; i < 2; ++i)
#pragma unroll
      for (int j = 0; j < 4; ++j) {
        const int row = r0 + mi * 32 + i * 16;
        const int col = c0 + j * 16;
#pragma unroll
        for (int r = 0; r < 4; ++r) {
          const float v = acc[mi * 2 + i][j][r];
          if (EPI == 0)
            Cb[cbase + (size_t)(row + r) * ldc + col] = __float2bfloat16(v);
          else if (EPI == 1)
            Ch[cbase + (size_t)(row + r) * ldc + col] = __float2half(v * scale);
          else
            Cf[cbase + (size_t)(row + r) * ldc + col] = v + bias[col];
        }
      }
}

#define GEMM_WRAP(NAME, EPI)                                                   \
  __global__ __launch_bounds__(512, 1) void NAME(                              \
      const __hip_bfloat16* __restrict__ A,                                    \
      const __hip_bfloat16* __restrict__ Bm, void* __restrict__ Cv,            \
      const float* __restrict__ bias, int N, int K, int lda, int ldb,          \
      int ldc, float scale, long strideA, long strideB, long strideC) {        \
    gemm8_body<EPI>(A, Bm, Cv, bias, N, K, lda, ldb, ldc, scale, strideA,      \
                    strideB, strideC);                                         \
  }
GEMM_WRAP(g_qkproj, 0)
GEMM_WRAP(g_vt, 0)
GEMM_WRAP(g_qkt, 1)
GEMM_WRAP(g_pv, 0)
GEMM_WRAP(g_out, 2)

// one block per 4096-wide row: read fp16 logits, write bf16 probs IN PLACE
__global__ __launch_bounds__(256) void softmax_inplace(void* __restrict__ buf) {
  const int t = threadIdx.x;
  unsigned short* rp = (unsigned short*)buf + (size_t)blockIdx.x * S_;
  ushort8 h0 = ((const ushort8*)rp)[t * 2];
  ushort8 h1 = ((const ushort8*)rp)[t * 2 + 1];
  float v[16];
#pragma unroll
  for (int j = 0; j < 8; ++j) {
    v[j] = __half2float(__builtin_bit_cast(__half, (unsigned short)h0[j]));
    v[8 + j] = __half2float(__builtin_bit_cast(__half, (unsigned short)h1[j]));
  }
  float m = -1e30f;
#pragma unroll
  for (int j = 0; j < 16; ++j) m = fmaxf(m, v[j]);
#pragma unroll
  for (int off = 32; off > 0; off >>= 1) m = fmaxf(m, __shfl_xor(m, off));
  __shared__ float red[8];
  const int wv = t >> 6;
  if ((t & 63) == 0) red[wv] = m;
  __syncthreads();
  m = fmaxf(fmaxf(red[0], red[1]), fmaxf(red[2], red[3]));
  float e[16], s = 0.f;
#pragma unroll
  for (int j = 0; j < 16; ++j) {
    e[j] = __expf(v[j] - m);
    s += e[j];
  }
#pragma unroll
  for (int off = 32; off > 0; off >>= 1) s += __shfl_xor(s, off);
  if ((t & 63) == 0) red[4 + wv] = s;
  __syncthreads();
  s = (red[4] + red[5]) + (red[6] + red[7]);
  const float inv = 1.0f / s;
  ushort8 o0, o1;
#pragma unroll
  for (int j = 0; j < 8; ++j) {
    o0[j] = f2bf(e[j] * inv);
    o1[j] = f2bf(e[8 + j] * inv);
  }
  ((ushort8*)rp)[t * 2] = o0;
  ((ushort8*)rp)[t * 2 + 1] = o1;
}

// fused cast: x (16384 blocks) + Wq,Wk,Wv,Wo (2048 blocks each), 8 elems/thr
__global__ __launch_bounds__(256) void cast_all(
    const float* __restrict__ x, const float* __restrict__ wq,
    const float* __restrict__ wk, const float* __restrict__ wv,
    const float* __restrict__ wo, __hip_bfloat16* __restrict__ xb,
    __hip_bfloat16* __restrict__ wqkb, __hip_bfloat16* __restrict__ wvb,
    __hip_bfloat16* __restrict__ wob) {
  const int b = blockIdx.x;
  const float* src;
  __hip_bfloat16* dst;
  long base;
  if (b < 16384) {
    src = x; dst = xb; base = (long)b;
  } else if (b < 18432) {
    src = wq; dst = wqkb; base = (long)(b - 16384);
  } else if (b < 20480) {
    src = wk; dst = wqkb + (long)DA_ * DM_; base = (long)(b - 18432);
  } else if (b < 22528) {
    src = wv; dst = wvb; base = (long)(b - 20480);
  } else {
    src = wo; dst = wob; base = (long)(b - 22528);
  }
  const long i = (base * 256 + threadIdx.x) * 8;
  const f32x4 a = *(const f32x4*)(src + i);
  const f32x4 c = *(const f32x4*)(src + i + 4);
  ushort8 o;
#pragma unroll
  for (int j = 0; j < 4; ++j) o[j] = f2bf(a[j]);
#pragma unroll
  for (int j = 0; j < 4; ++j) o[4 + j] = f2bf(c[j]);
  *(ushort8*)(dst + i) = o;
}

extern "C" void kernel_launch(void* const* d_in, const int* in_sizes, int n_in,
                              void* d_out, int out_size, void* d_ws,
                              size_t ws_size, hipStream_t stream) {
  (void)in_sizes; (void)n_in; (void)out_size;
  const float* x = (const float*)d_in[0];
  const float* Wq = (const float*)d_in[1];
  const float* Wk = (const float*)d_in[2];
  const float* Wv = (const float*)d_in[3];
  const float* Wo = (const float*)d_in[4];
  const float* bo = (const float*)d_in[5];
  float* out = (float*)d_out;

  const long MB = 1ll << 20;
  char* ws = (char*)d_ws;
  __hip_bfloat16* Xb   = (__hip_bfloat16*)(ws);             // 64 MiB
  __hip_bfloat16* QKb  = (__hip_bfloat16*)(ws + 64 * MB);   // 128 MiB (Q|K)
  __hip_bfloat16* Vt   = (__hip_bfloat16*)(ws + 192 * MB);  // 64 MiB
  __hip_bfloat16* Wqkb = (__hip_bfloat16*)(ws + 256 * MB);  // 16 MiB
  __hip_bfloat16* Wvb  = (__hip_bfloat16*)(ws + 272 * MB);  // 8 MiB
  __hip_bfloat16* Wob  = (__hip_bfloat16*)(ws + 280 * MB);  // 8 MiB
  char* LgP            = ws + 288 * MB;  // 128 MiB batched / 32 MiB per-batch
  __hip_bfloat16* AO = Xb;  // x dead after projections; reuse

  const bool batched = ws_size >= (size_t)(416 * MB);

  cast_all<<<dim3(24576), dim3(256), 0, stream>>>(x, Wq, Wk, Wv, Wo, Xb, Wqkb,
                                                  Wvb, Wob);

  // fused Q|K projection: [16384, 4096] = Xb @ [Wq;Wk]^T
  g_qkproj<<<dim3(1024, 1), dim3(512), 0, stream>>>(
      Xb, Wqkb, QKb, nullptr, 4096, 2048, 2048, 2048, 4096, 1.f, 0, 0, 0);
  // Vt (batched): [2048, 4096] = Wv @ Xb_b^T
  g_vt<<<dim3(128, NB_), dim3(512), 0, stream>>>(
      Wvb, Xb, Vt, nullptr, 4096, 2048, 2048, 2048, 4096, 1.f, 0,
      (long)S_ * DM_, (long)DA_ * S_);

  const float scale = 0.022097086912079608f;  // 1/sqrt(d_model=2048)
  if (batched) {
    g_qkt<<<dim3(256, NB_), dim3(512), 0, stream>>>(
        QKb, QKb + DA_, LgP, nullptr, 4096, 2048, 4096, 4096, 4096, scale,
        (long)S_ * 2 * DA_, (long)S_ * 2 * DA_, (long)S_ * S_);
    softmax_inplace<<<dim3(NB_ * S_), dim3(256), 0, stream>>>(LgP);
    g_pv<<<dim3(128, NB_), dim3(512), 0, stream>>>(
        (const __hip_bfloat16*)LgP, Vt, AO, nullptr, 2048, 4096, 4096, 4096,
        2048, 1.f, (long)S_ * S_, (long)DA_ * S_, (long)S_ * DA_);
  } else {
    for (int b = 0; b < NB_; ++b) {
      const __hip_bfloat16* Qb = QKb + (size_t)b * S_ * 2 * DA_;
      g_qkt<<<dim3(256, 1), dim3(512), 0, stream>>>(
          Qb, Qb + DA_, LgP, nullptr, 4096, 2048, 4096, 4096, 4096, scale, 0,
          0, 0);
      softmax_inplace<<<dim3(S_), dim3(256), 0, stream>>>(LgP);
      g_pv<<<dim3(128, 1), dim3(512), 0, stream>>>(
          (const __hip_bfloat16*)LgP, Vt + (size_t)b * DA_ * S_,
          AO + (size_t)b * S_ * DA_, nullptr, 2048, 4096, 4096, 4096, 2048,
          1.f, 0, 0, 0);
    }
  }
  // out = AO @ Wo^T + bo (fp32)
  g_out<<<dim3(512, 1), dim3(512), 0, stream>>>(
      AO, Wob, out, bo, 2048, 2048, 2048, 2048, 2048, 1.f, 0, 0, 0);
}